// Round 1
// baseline (98.774 us; speedup 1.0000x reference)
//
#include <hip/hip_runtime.h>

// SeqSelfAttention: additive (Bahdanau) local attention, centered band width 64.
// B=2, L=1024, D=256, U=64. All f32.
// Exact-equivalence notes:
//  - masked logits underflow to exp()==0.0f in f32, so band-only softmax is exact.
//  - ba[0] is softmax-invariant -> dropped. bh folded into q.

#define NROWS 2048   // B*L
#define LSEQ  1024
#define DDIM  256
#define UDIM  64

__global__ __launch_bounds__(256) void qk_kernel(
    const float* __restrict__ x, const float* __restrict__ Wt,
    const float* __restrict__ Wx, const float* __restrict__ bh,
    float* __restrict__ q, float* __restrict__ kT) {
  int t   = threadIdx.x;
  int u   = t & 63;
  int sel = (t >> 6) & 1;                 // 0 -> q (Wt), 1 -> k (Wx)
  int row = blockIdx.x * 2 + (t >> 7);    // two rows per block
  const float* __restrict__ W = sel ? Wx : Wt;
  const float4* __restrict__ xr = (const float4*)(x + row * DDIM);
  float acc = 0.f;
#pragma unroll 8
  for (int d4 = 0; d4 < DDIM / 4; ++d4) {
    float4 xv = xr[d4];                   // broadcast across the wave (L1/L2 hit)
    const float* wp = W + d4 * 4 * UDIM + u;  // lane-coalesced
    acc += xv.x * wp[0] + xv.y * wp[64] + xv.z * wp[128] + xv.w * wp[192];
  }
  if (sel == 0) q[row * UDIM + u] = acc + bh[u];   // fold bh into q
  else          kT[u * NROWS + row] = acc;         // transposed for coalesced reads
}

__device__ __forceinline__ float tanh_fast(float v) {
  // tanh(x) = 2/(1+e^{-2x}) - 1 ; correct saturation at +/-inf of exp.
  float t = __expf(-2.f * v);
  return 2.f * __builtin_amdgcn_rcpf(1.f + t) - 1.f;
}

__global__ __launch_bounds__(256) void attn_kernel(
    const float* __restrict__ x, const float* __restrict__ q,
    const float* __restrict__ kT, const float* __restrict__ Wa,
    float* __restrict__ out) {
  int lane = threadIdx.x & 63;
  int wid  = threadIdx.x >> 6;            // 4 waves/block, one row each
  int grow = blockIdx.x * 4 + wid;        // global row in [0, 2048)
  int b = grow >> 10;
  int i = grow & (LSEQ - 1);
  int lo = max(0, i - 32);
  int hi = min(LSEQ, i + 32);

  __shared__ float qs[4][UDIM];
  __shared__ float was[UDIM];
  qs[wid][lane] = q[grow * UDIM + lane];
  if (threadIdx.x < UDIM) was[threadIdx.x] = Wa[threadIdx.x];
  __syncthreads();

  // ---- logits: lane <-> window column j ----
  int  j     = lo + lane;
  bool valid = j < hi;
  int  jc    = valid ? j : hi - 1;        // clamp to stay in-bounds
  const float* __restrict__ kp = kT + b * LSEQ + jc;
  float e = 0.f;
#pragma unroll 8
  for (int u = 0; u < UDIM; ++u) {
    float kv = kp[u * NROWS];             // lane-coalesced (kT layout)
    e += was[u] * tanh_fast(qs[wid][u] + kv);
  }

  // ---- wave-wide masked softmax ----
  float m = valid ? e : -3.4e38f;
#pragma unroll
  for (int off = 32; off >= 1; off >>= 1) m = fmaxf(m, __shfl_xor(m, off));
  float p = valid ? __expf(e - m) : 0.f;
  float s = p;
#pragma unroll
  for (int off = 32; off >= 1; off >>= 1) s += __shfl_xor(s, off);
  float a = p * __builtin_amdgcn_rcpf(s);

  // ---- v_i = sum_j a_j * x_j ; lane <-> 4 d-columns (float4) ----
  const float4* __restrict__ xb = (const float4*)(x + (b * LSEQ + lo) * DDIM);
  float4 acc = make_float4(0.f, 0.f, 0.f, 0.f);
  int wlen = hi - lo;
  if (wlen == 64) {
#pragma unroll 8
    for (int jj = 0; jj < 64; ++jj) {
      float aj = __shfl(a, jj);
      float4 xv = xb[jj * 64 + lane];
      acc.x += aj * xv.x; acc.y += aj * xv.y; acc.z += aj * xv.z; acc.w += aj * xv.w;
    }
  } else {
    for (int jj = 0; jj < wlen; ++jj) {
      float aj = __shfl(a, jj);
      float4 xv = xb[jj * 64 + lane];
      acc.x += aj * xv.x; acc.y += aj * xv.y; acc.z += aj * xv.z; acc.w += aj * xv.w;
    }
  }
  float4* o4 = (float4*)(out + grow * DDIM);
  o4[lane] = acc;
}

extern "C" void kernel_launch(void* const* d_in, const int* in_sizes, int n_in,
                              void* d_out, int out_size, void* d_ws, size_t ws_size,
                              hipStream_t stream) {
  const float* x  = (const float*)d_in[0];
  const float* Wt = (const float*)d_in[1];
  const float* Wx = (const float*)d_in[2];
  const float* bh = (const float*)d_in[3];
  const float* Wa = (const float*)d_in[4];
  // d_in[5] = ba : softmax-invariant, unused.
  float* out = (float*)d_out;

  float* q  = (float*)d_ws;            // [2048][64]
  float* kT = q + NROWS * UDIM;        // [64][2048]

  qk_kernel<<<NROWS / 2, 256, 0, stream>>>(x, Wt, Wx, bh, q, kT);
  attn_kernel<<<NROWS / 4, 256, 0, stream>>>(x, q, kT, Wa, out);
}

// Round 2
// 90.826 us; speedup vs baseline: 1.0875x; 1.0875x over previous
//
#include <hip/hip_runtime.h>

// SeqSelfAttention: additive (Bahdanau) local attention, centered band width 64.
// B=2, L=1024, D=256, U=64, all f32.
// Exactness: masked logits underflow to exp()==0 in f32 -> band-only softmax is
// exact; ba[0] softmax-invariant -> dropped; bh folded into q.

#define LSEQ  1024
#define DDIM  256
#define UDIM  64
#define NROWS 2048
#define RPB   4      // rows per attn block
#define JMAX  68     // padded window-union width (<=67 real)

// ---------------- qk: q[r][u] = x[r].Wt[:,u] + bh[u] ; k[r][u] = x[r].Wx[:,u]
// 256 threads / block, 8 rows / block (4 rows per thread, W loads reused 4x).
__global__ __launch_bounds__(256) void qk_kernel(
    const float* __restrict__ x, const float* __restrict__ Wt,
    const float* __restrict__ Wx, const float* __restrict__ bh,
    float* __restrict__ q, float* __restrict__ k) {
  int t = threadIdx.x;
  int u = t & 63;
  int sel = (t >> 6) & 1;                  // 0 -> q (Wt), 1 -> k (Wx)
  int r0 = blockIdx.x * 8 + (t >> 7) * 4;  // 4 consecutive rows per thread
  const float* __restrict__ W = sel ? Wx : Wt;
  const float4* __restrict__ x0 = (const float4*)(x + (r0 + 0) * DDIM);
  const float4* __restrict__ x1 = (const float4*)(x + (r0 + 1) * DDIM);
  const float4* __restrict__ x2 = (const float4*)(x + (r0 + 2) * DDIM);
  const float4* __restrict__ x3 = (const float4*)(x + (r0 + 3) * DDIM);
  float a0 = 0.f, a1 = 0.f, a2 = 0.f, a3 = 0.f;
#pragma unroll 4
  for (int d4 = 0; d4 < DDIM / 4; ++d4) {
    const float* wp = W + d4 * 4 * UDIM + u;    // lane-coalesced
    float w0 = wp[0], w1 = wp[64], w2 = wp[128], w3 = wp[192];
    float4 v0 = x0[d4], v1 = x1[d4], v2 = x2[d4], v3 = x3[d4];  // wave-uniform
    a0 += v0.x * w0 + v0.y * w1 + v0.z * w2 + v0.w * w3;
    a1 += v1.x * w0 + v1.y * w1 + v1.z * w2 + v1.w * w3;
    a2 += v2.x * w0 + v2.y * w1 + v2.z * w2 + v2.w * w3;
    a3 += v3.x * w0 + v3.y * w1 + v3.z * w2 + v3.w * w3;
  }
  float* __restrict__ dst = sel ? k : q;
  float bias = sel ? 0.f : bh[u];
  dst[(r0 + 0) * UDIM + u] = a0 + bias;    // coalesced row-major stores
  dst[(r0 + 1) * UDIM + u] = a1 + bias;
  dst[(r0 + 2) * UDIM + u] = a2 + bias;
  dst[(r0 + 3) * UDIM + u] = a3 + bias;
}

__device__ __forceinline__ float tanh_fast(float v) {
  float t = __expf(-2.f * v);
  return 2.f * __builtin_amdgcn_rcpf(1.f + t) - 1.f;
}

__device__ __forceinline__ float bcast(float v, int l) {
  return __uint_as_float(__builtin_amdgcn_readlane(__float_as_uint(v), l));
}

// ---------------- attn: 4 rows / block, k-window staged in LDS, shared-x PV.
__global__ __launch_bounds__(256) void attn_kernel(
    const float* __restrict__ x, const float* __restrict__ q,
    const float* __restrict__ k, const float* __restrict__ Wa,
    float* __restrict__ out) {
  __shared__ float k_lds[JMAX][UDIM + 1];  // pitch 65 words -> conflict-free
  __shared__ float a_lds[RPB][JMAX];       // softmax weights, abs window coords

  int t = threadIdx.x;
  int lane = t & 63;
  int wid = t >> 6;                        // 4 waves
  int g0 = blockIdx.x * RPB;               // first global row
  int b = g0 >> 10;
  int i0 = g0 & (LSEQ - 1);
  int jbase = max(0, i0 - 32);
  int jend = min(LSEQ, i0 + RPB - 1 + 32); // max hi over block rows
  int jcount = jend - jbase;

  // ---- stage k window (coalesced 256B per row) + zero a_lds ----
  for (int jj = wid; jj < jcount; jj += 4)
    k_lds[jj][lane] = k[(b * LSEQ + jbase + jj) * UDIM + lane];
  for (int z = t; z < RPB * JMAX; z += 256) ((float*)a_lds)[z] = 0.f;
  // q row + Wa in registers; broadcast via readlane (off the LDS pipe)
  float qv = q[(g0 + wid) * UDIM + lane];
  float wv = Wa[lane];
  __syncthreads();

  // ---- logits: wave wid owns row i0+wid, lane <-> window column ----
  int i = i0 + wid;
  int lo = max(0, i - 32);
  int hi = min(LSEQ, i + 32);
  int off = lo - jbase;                    // window offset inside LDS union
  bool valid = (lo + lane) < hi;
  const float* __restrict__ kr = &k_lds[off + lane][0];
  float e = 0.f;
#pragma unroll
  for (int u = 0; u < UDIM; ++u)
    e += bcast(wv, u) * tanh_fast(bcast(qv, u) + kr[u]);

  // ---- wave softmax (invalid lanes contribute 0) ----
  float m = valid ? e : -3.4e38f;
#pragma unroll
  for (int o = 32; o >= 1; o >>= 1) m = fmaxf(m, __shfl_xor(m, o));
  float p = valid ? __expf(e - m) : 0.f;
  float s = p;
#pragma unroll
  for (int o = 32; o >= 1; o >>= 1) s += __shfl_xor(s, o);
  a_lds[wid][off + lane] = p * __builtin_amdgcn_rcpf(s);
  __syncthreads();

  // ---- PV: wave wid owns dims [wid*64, wid*64+64); share x rows over 4 rows --
  const float* __restrict__ xq = x + b * LSEQ * DDIM + wid * 64 + lane;
  float c0 = 0.f, c1 = 0.f, c2 = 0.f, c3 = 0.f;
  int nch = (jcount + 3) >> 2;
  for (int ch = 0; ch < nch; ++ch) {
    int jj = ch * 4;
    float4 A0 = *(const float4*)&a_lds[0][jj];  // wave-uniform broadcasts
    float4 A1 = *(const float4*)&a_lds[1][jj];
    float4 A2 = *(const float4*)&a_lds[2][jj];
    float4 A3 = *(const float4*)&a_lds[3][jj];
    int j0 = jbase + jj;
    float xv0 = xq[min(j0 + 0, jend - 1) * DDIM];  // clamped; a==0 past jcount
    float xv1 = xq[min(j0 + 1, jend - 1) * DDIM];
    float xv2 = xq[min(j0 + 2, jend - 1) * DDIM];
    float xv3 = xq[min(j0 + 3, jend - 1) * DDIM];
    c0 += A0.x * xv0 + A0.y * xv1 + A0.z * xv2 + A0.w * xv3;
    c1 += A1.x * xv0 + A1.y * xv1 + A1.z * xv2 + A1.w * xv3;
    c2 += A2.x * xv0 + A2.y * xv1 + A2.z * xv2 + A2.w * xv3;
    c3 += A3.x * xv0 + A3.y * xv1 + A3.z * xv2 + A3.w * xv3;
  }
  float* __restrict__ ob = out + g0 * DDIM + wid * 64 + lane;
  ob[0 * DDIM] = c0;
  ob[1 * DDIM] = c1;
  ob[2 * DDIM] = c2;
  ob[3 * DDIM] = c3;
}

extern "C" void kernel_launch(void* const* d_in, const int* in_sizes, int n_in,
                              void* d_out, int out_size, void* d_ws, size_t ws_size,
                              hipStream_t stream) {
  const float* x  = (const float*)d_in[0];
  const float* Wt = (const float*)d_in[1];
  const float* Wx = (const float*)d_in[2];
  const float* bh = (const float*)d_in[3];
  const float* Wa = (const float*)d_in[4];
  // d_in[5] = ba : softmax-invariant, unused.
  float* out = (float*)d_out;

  float* q = (float*)d_ws;            // [2048][64]
  float* k = q + NROWS * UDIM;        // [2048][64]

  qk_kernel<<<NROWS / 8, 256, 0, stream>>>(x, Wt, Wx, bh, q, k);
  attn_kernel<<<NROWS / RPB, 256, 0, stream>>>(x, q, k, Wa, out);
}

// Round 3
// 89.255 us; speedup vs baseline: 1.1066x; 1.0176x over previous
//
#include <hip/hip_runtime.h>

// SeqSelfAttention: additive (Bahdanau) local attention, centered band width 64.
// B=2, L=1024, D=256, U=64, all f32.
// Exactness: masked logits underflow to exp()==0 in f32 -> band-only softmax is
// exact; ba[0] softmax-invariant -> dropped; bh folded into q.
// q,k are stored PRESCALED by -2*log2(e) so the logit loop's tanh is:
//   t = exp2(q'+k');  tanh = 2*rcp(1+t) - 1
// and e = Wa.tanh = 2*sum(wa*rcp(1+t)) - sum(wa)  (sum(wa) hoisted).

#define LSEQ  1024
#define DDIM  256
#define UDIM  64
#define NROWS 2048
#define RPB   4      // rows per attn block
#define JMAX  68     // padded window-union width (<=67 real)

#if __has_builtin(__builtin_amdgcn_exp2f)
#define EXPFN(x) __builtin_amdgcn_exp2f(x)
#define PRESCALE -2.8853900817779268f   // -2*log2(e)
#else
#define EXPFN(x) __expf(x)
#define PRESCALE -2.0f
#endif

// ---------------- qk: q'[r][u] = S*(x[r].Wt[:,u] + bh[u]) ; k'[r][u] = S*x[r].Wx[:,u]
// 512 blocks, 256 threads, 2 rows/thread (2 waves/SIMD for latency hiding).
__global__ __launch_bounds__(256) void qk_kernel(
    const float* __restrict__ x, const float* __restrict__ Wt,
    const float* __restrict__ Wx, const float* __restrict__ bh,
    float* __restrict__ q, float* __restrict__ k) {
  int t = threadIdx.x;
  int u = t & 63;
  int sel = (t >> 6) & 1;                  // 0 -> q (Wt), 1 -> k (Wx)
  int r0 = blockIdx.x * 4 + (t >> 7) * 2;  // 2 consecutive rows per thread
  const float* __restrict__ W = sel ? Wx : Wt;
  const float4* __restrict__ x0 = (const float4*)(x + (r0 + 0) * DDIM);
  const float4* __restrict__ x1 = (const float4*)(x + (r0 + 1) * DDIM);
  float a0 = 0.f, a1 = 0.f;
#pragma unroll 8
  for (int d4 = 0; d4 < DDIM / 4; ++d4) {
    const float* wp = W + d4 * 4 * UDIM + u;    // lane-coalesced
    float w0 = wp[0], w1 = wp[64], w2 = wp[128], w3 = wp[192];
    float4 v0 = x0[d4], v1 = x1[d4];            // wave-uniform (scalarizable)
    a0 += v0.x * w0 + v0.y * w1 + v0.z * w2 + v0.w * w3;
    a1 += v1.x * w0 + v1.y * w1 + v1.z * w2 + v1.w * w3;
  }
  float bias = sel ? 0.f : bh[u];
  float* __restrict__ dst = sel ? k : q;
  dst[(r0 + 0) * UDIM + u] = PRESCALE * (a0 + bias);   // coalesced stores
  dst[(r0 + 1) * UDIM + u] = PRESCALE * (a1 + bias);
}

// ---------------- attn: 4 rows / block, k-window staged in LDS, shared-x PV.
__global__ __launch_bounds__(256) void attn_kernel(
    const float* __restrict__ x, const float* __restrict__ q,
    const float* __restrict__ k, const float* __restrict__ Wa,
    float* __restrict__ out) {
  __shared__ float k_lds[JMAX][UDIM + 1];  // pitch 65 words -> conflict-free b32
  __shared__ float qs[RPB][UDIM];          // prescaled q rows (256B aligned)
  __shared__ float was[UDIM];              // Wa (for float4 broadcasts)
  __shared__ float a_lds[RPB][JMAX];       // softmax weights (rows 16B aligned)

  int t = threadIdx.x;
  int lane = t & 63;
  int wid = t >> 6;                        // 4 waves
  int g0 = blockIdx.x * RPB;
  int b = g0 >> 10;
  int i0 = g0 & (LSEQ - 1);
  int jbase = max(0, i0 - 32);
  int jend = min(LSEQ, i0 + RPB - 1 + 32);
  int jcount = jend - jbase;

  // ---- stage k window + q rows + Wa; zero a_lds; hoist sum(wa) ----
  for (int jj = wid; jj < jcount; jj += 4)
    k_lds[jj][lane] = k[(b * LSEQ + jbase + jj) * UDIM + lane];
  qs[wid][lane] = q[(g0 + wid) * UDIM + lane];
  float wv = Wa[lane];
  if (wid == 0) was[lane] = wv;
  for (int z = t; z < RPB * JMAX; z += 256) ((float*)a_lds)[z] = 0.f;
  float swa = wv;                          // sum(wa) via wave reduce
#pragma unroll
  for (int o = 32; o >= 1; o >>= 1) swa += __shfl_xor(swa, o);
  __syncthreads();

  // ---- logits: wave wid owns row i0+wid, lane <-> window column ----
  int i = i0 + wid;
  int lo = max(0, i - 32);
  int hi = min(LSEQ, i + 32);
  int off = lo - jbase;
  bool valid = (lo + lane) < hi;
  const float* __restrict__ kr = &k_lds[off + lane][0];
  float e2 = 0.f;
#pragma unroll
  for (int u4 = 0; u4 < UDIM; u4 += 4) {
    float4 q4 = *(const float4*)&qs[wid][u4];   // wave-uniform b128 broadcast
    float4 w4 = *(const float4*)&was[u4];       // wave-uniform b128 broadcast
    float t0 = EXPFN(q4.x + kr[u4 + 0]);
    float t1 = EXPFN(q4.y + kr[u4 + 1]);
    float t2 = EXPFN(q4.z + kr[u4 + 2]);
    float t3 = EXPFN(q4.w + kr[u4 + 3]);
    e2 += w4.x * __builtin_amdgcn_rcpf(1.f + t0);
    e2 += w4.y * __builtin_amdgcn_rcpf(1.f + t1);
    e2 += w4.z * __builtin_amdgcn_rcpf(1.f + t2);
    e2 += w4.w * __builtin_amdgcn_rcpf(1.f + t3);
  }
  float e = 2.f * e2 - swa;

  // ---- wave softmax (invalid lanes contribute 0) ----
  float m = valid ? e : -3.4e38f;
#pragma unroll
  for (int o = 32; o >= 1; o >>= 1) m = fmaxf(m, __shfl_xor(m, o));
  float p = valid ? __expf(e - m) : 0.f;
  float s = p;
#pragma unroll
  for (int o = 32; o >= 1; o >>= 1) s += __shfl_xor(s, o);
  a_lds[wid][off + lane] = p * __builtin_amdgcn_rcpf(s);
  __syncthreads();

  // ---- PV: wave wid owns dims [wid*64, wid*64+64); x rows shared over 4 rows --
  const float* __restrict__ xq = x + b * LSEQ * DDIM + wid * 64 + lane;
  float c0 = 0.f, c1 = 0.f, c2 = 0.f, c3 = 0.f;
  int nch = (jcount + 3) >> 2;
  for (int ch = 0; ch < nch; ++ch) {
    int jj = ch * 4;
    float4 A0 = *(const float4*)&a_lds[0][jj];  // wave-uniform broadcasts
    float4 A1 = *(const float4*)&a_lds[1][jj];
    float4 A2 = *(const float4*)&a_lds[2][jj];
    float4 A3 = *(const float4*)&a_lds[3][jj];
    int j0 = jbase + jj;
    float xv0 = xq[min(j0 + 0, jend - 1) * DDIM];  // clamped; a==0 past jcount
    float xv1 = xq[min(j0 + 1, jend - 1) * DDIM];
    float xv2 = xq[min(j0 + 2, jend - 1) * DDIM];
    float xv3 = xq[min(j0 + 3, jend - 1) * DDIM];
    c0 += A0.x * xv0 + A0.y * xv1 + A0.z * xv2 + A0.w * xv3;
    c1 += A1.x * xv0 + A1.y * xv1 + A1.z * xv2 + A1.w * xv3;
    c2 += A2.x * xv0 + A2.y * xv1 + A2.z * xv2 + A2.w * xv3;
    c3 += A3.x * xv0 + A3.y * xv1 + A3.z * xv2 + A3.w * xv3;
  }
  float* __restrict__ ob = out + g0 * DDIM + wid * 64 + lane;
  ob[0 * DDIM] = c0;
  ob[1 * DDIM] = c1;
  ob[2 * DDIM] = c2;
  ob[3 * DDIM] = c3;
}

extern "C" void kernel_launch(void* const* d_in, const int* in_sizes, int n_in,
                              void* d_out, int out_size, void* d_ws, size_t ws_size,
                              hipStream_t stream) {
  const float* x  = (const float*)d_in[0];
  const float* Wt = (const float*)d_in[1];
  const float* Wx = (const float*)d_in[2];
  const float* bh = (const float*)d_in[3];
  const float* Wa = (const float*)d_in[4];
  // d_in[5] = ba : softmax-invariant, unused.
  float* out = (float*)d_out;

  float* q = (float*)d_ws;            // [2048][64] prescaled
  float* k = q + NROWS * UDIM;        // [2048][64] prescaled

  qk_kernel<<<NROWS / 4, 256, 0, stream>>>(x, Wt, Wx, bh, q, k);
  attn_kernel<<<NROWS / RPB, 256, 0, stream>>>(x, q, k, Wa, out);
}